// Round 3
// baseline (924.171 us; speedup 1.0000x reference)
//
#include <hip/hip_runtime.h>
#include <hip/hip_bf16.h>
#include <math.h>

#define BB 4
#define NN 512
#define DD 64
#define HH 8
#define DKK 8

// ---------------- Kernel 1: QKV projection ----------------
__global__ __launch_bounds__(64) void qkv_kernel(
    const float* __restrict__ n,
    const float* __restrict__ Wq,
    const float* __restrict__ Wk,
    const float* __restrict__ Wv,
    float* __restrict__ Q,
    float* __restrict__ K,
    float* __restrict__ V)
{
    const int row = blockIdx.x;        // b*N + i
    const int j = threadIdx.x;         // 0..63
    __shared__ __align__(16) float nr[DD];
    nr[j] = n[(size_t)row * DD + j];
    __syncthreads();
    float q = 0.f, k = 0.f, v = 0.f;
#pragma unroll
    for (int d = 0; d < DD; ++d) {
        const float nv = nr[d];
        q = fmaf(nv, Wq[d * DD + j], q);
        k = fmaf(nv, Wk[d * DD + j], k);
        v = fmaf(nv, Wv[d * DD + j], v);
    }
    Q[(size_t)row * DD + j] = q;
    K[(size_t)row * DD + j] = k;
    V[(size_t)row * DD + j] = v;
}

// ---------------- Kernel 2: fused edge + attention ----------------
// One block of 256 threads per (b, i). Thread t handles m = t and m = t+256.
// Phase 1: A = clip(QK^T * scale) -> eb_lds.   Phase 2: stream e, add E, e_out.
// __launch_bounds__(256,4): cap 128 VGPR -> 4 blocks/CU.
__global__ __launch_bounds__(256, 4) void attn_kernel(
    const float* __restrict__ e,
    const float* __restrict__ Q,
    const float* __restrict__ K,
    const float* __restrict__ V,
    const float* __restrict__ We,   // [64][8]
    const float* __restrict__ Wg,   // [64][8]
    const float* __restrict__ Oe,   // [8][64]
    const float* __restrict__ On,   // [64][64]
    float* __restrict__ n_out,      // [B][N][64]
    float* __restrict__ e_out)      // [B][N][N][64]
{
    const int row = blockIdx.x;        // b*N + i
    const int b = row >> 9;            // row / 512
    const int t = threadIdx.x;
    const int lane = t & 63;
    const int wv = t >> 6;             // wave id 0..3

    __shared__ __align__(16) float we_l[DD * HH];   // 2 KB
    __shared__ __align__(16) float wg_l[DD * HH];   // 2 KB
    __shared__ __align__(16) float oe_l[HH * DD];   // 2 KB
    __shared__ __align__(16) float q_lds[DD];
    __shared__ float eb_lds[HH][NN];   // 16 KB
    __shared__ float gpart[4][HH];
    __shared__ float gsum[HH];
    __shared__ float vh_lds[DD];

    // stage weights (6 KB) + q once per block
#pragma unroll
    for (int idx = t; idx < DD * HH; idx += 256) {
        we_l[idx] = We[idx];
        wg_l[idx] = Wg[idx];
        oe_l[idx] = Oe[idx];
    }
    if (t < DD) q_lds[t] = Q[(size_t)row * DD + t];
    __syncthreads();

    const float scale = 0.35355339059327373f;  // 1/sqrt(8)
    const float* __restrict__ Kb = K + (size_t)b * NN * DD;

    // ---- Phase 1: A = clip(Q.K * scale) into eb_lds ----
    for (int mm = 0; mm < 2; ++mm) {
        const int m = t + mm * 256;
        const float4* __restrict__ kr = (const float4*)(Kb + (size_t)m * DD);
        float aa[HH];
#pragma unroll
        for (int h = 0; h < HH; ++h) {
            const float4 k0 = kr[2 * h];
            const float4 k1 = kr[2 * h + 1];
            const float4 q0 = *(const float4*)&q_lds[h * 8];
            const float4 q1 = *(const float4*)&q_lds[h * 8 + 4];
            float a = q0.x * k0.x;
            a = fmaf(q0.y, k0.y, a);
            a = fmaf(q0.z, k0.z, a);
            a = fmaf(q0.w, k0.w, a);
            a = fmaf(q1.x, k1.x, a);
            a = fmaf(q1.y, k1.y, a);
            a = fmaf(q1.z, k1.z, a);
            a = fmaf(q1.w, k1.w, a);
            aa[h] = a;
        }
#pragma unroll
        for (int h = 0; h < HH; ++h) {
            float a = aa[h] * scale;
            eb_lds[h][m] = fminf(fmaxf(a, -5.f), 5.f);
        }
    }
    // no barrier needed: each thread reads back only its own eb_lds entries

    float gs[HH];
#pragma unroll
    for (int h = 0; h < HH; ++h) gs[h] = 0.f;

    const float* __restrict__ e_row_base = e + (size_t)row * NN * DD;
    float* __restrict__ eo_base = e_out + (size_t)row * NN * DD;

    // ---- Phase 2: stream e, compute E/G, Eb, e_out ----
    for (int mm = 0; mm < 2; ++mm) {
        const int m = t + mm * 256;
        const float4* __restrict__ er = (const float4*)(e_row_base + (size_t)m * DD);

        float ea[HH], ga[HH];
#pragma unroll
        for (int h = 0; h < HH; ++h) { ea[h] = 0.f; ga[h] = 0.f; }

#pragma unroll 8
        for (int c = 0; c < DD / 4; ++c) {     // 16 float4 chunks of e
            const float4 ev = er[c];
#pragma unroll
            for (int j = 0; j < 4; ++j) {
                const int d = c * 4 + j;
                const float evj = (j == 0) ? ev.x : (j == 1) ? ev.y : (j == 2) ? ev.z : ev.w;
                const float4 wea = *(const float4*)&we_l[d * HH];
                const float4 web = *(const float4*)&we_l[d * HH + 4];
                const float4 wga = *(const float4*)&wg_l[d * HH];
                const float4 wgb = *(const float4*)&wg_l[d * HH + 4];
                ea[0] = fmaf(evj, wea.x, ea[0]);
                ea[1] = fmaf(evj, wea.y, ea[1]);
                ea[2] = fmaf(evj, wea.z, ea[2]);
                ea[3] = fmaf(evj, wea.w, ea[3]);
                ea[4] = fmaf(evj, web.x, ea[4]);
                ea[5] = fmaf(evj, web.y, ea[5]);
                ea[6] = fmaf(evj, web.z, ea[6]);
                ea[7] = fmaf(evj, web.w, ea[7]);
                ga[0] = fmaf(evj, wga.x, ga[0]);
                ga[1] = fmaf(evj, wga.y, ga[1]);
                ga[2] = fmaf(evj, wga.z, ga[2]);
                ga[3] = fmaf(evj, wga.w, ga[3]);
                ga[4] = fmaf(evj, wgb.x, ga[4]);
                ga[5] = fmaf(evj, wgb.y, ga[5]);
                ga[6] = fmaf(evj, wgb.z, ga[6]);
                ga[7] = fmaf(evj, wgb.w, ga[7]);
            }
        }

        float eb[HH];
#pragma unroll
        for (int h = 0; h < HH; ++h) {
            const float ebv = eb_lds[h][m] + ea[h];   // A already clipped+scaled
            eb[h] = ebv;
            eb_lds[h][m] = ebv;
            gs[h] += 1.f / (1.f + expf(-ga[h]));
        }

        // e_out[b,i,m,:] = sum_h eb[h] * Oe[h][:]
        float4* __restrict__ eo = (float4*)(eo_base + (size_t)m * DD);
#pragma unroll
        for (int c = 0; c < DD / 4; ++c) {
            float4 acc;
            acc.x = 0.f; acc.y = 0.f; acc.z = 0.f; acc.w = 0.f;
#pragma unroll
            for (int h = 0; h < HH; ++h) {
                const float4 ov = *(const float4*)&oe_l[h * DD + c * 4];
                const float ebh = eb[h];
                acc.x = fmaf(ebh, ov.x, acc.x);
                acc.y = fmaf(ebh, ov.y, acc.y);
                acc.z = fmaf(ebh, ov.z, acc.z);
                acc.w = fmaf(ebh, ov.w, acc.w);
            }
            eo[c] = acc;
        }
    }

    // ---- deterministic G-sum reduction ----
#pragma unroll
    for (int h = 0; h < HH; ++h) {
        float x = gs[h];
        x += __shfl_xor(x, 1, 64);
        x += __shfl_xor(x, 2, 64);
        x += __shfl_xor(x, 4, 64);
        x += __shfl_xor(x, 8, 64);
        x += __shfl_xor(x, 16, 64);
        x += __shfl_xor(x, 32, 64);
        if (lane == 0) gpart[wv][h] = x;
    }
    __syncthreads();
    if (t < HH) gsum[t] = gpart[0][t] + gpart[1][t] + gpart[2][t] + gpart[3][t];
    __syncthreads();

    // ---- softmax + PV: wave wv handles h = wv and wv+4 ----
    const float* __restrict__ Vb = V + (size_t)b * NN * DD;
#pragma unroll
    for (int hh = 0; hh < 2; ++hh) {
        const int h = wv + hh * 4;
        float x[8];
#pragma unroll
        for (int k = 0; k < 8; ++k) x[k] = eb_lds[h][lane + (k << 6)];
        float mx = x[0];
#pragma unroll
        for (int k = 1; k < 8; ++k) mx = fmaxf(mx, x[k]);
        mx = fmaxf(mx, __shfl_xor(mx, 1, 64));
        mx = fmaxf(mx, __shfl_xor(mx, 2, 64));
        mx = fmaxf(mx, __shfl_xor(mx, 4, 64));
        mx = fmaxf(mx, __shfl_xor(mx, 8, 64));
        mx = fmaxf(mx, __shfl_xor(mx, 16, 64));
        mx = fmaxf(mx, __shfl_xor(mx, 32, 64));
        float p[8];
        float s = 0.f;
#pragma unroll
        for (int k = 0; k < 8; ++k) { p[k] = expf(x[k] - mx); s += p[k]; }
        s += __shfl_xor(s, 1, 64);
        s += __shfl_xor(s, 2, 64);
        s += __shfl_xor(s, 4, 64);
        s += __shfl_xor(s, 8, 64);
        s += __shfl_xor(s, 16, 64);
        s += __shfl_xor(s, 32, 64);

        float pv[8];
#pragma unroll
        for (int dk = 0; dk < 8; ++dk) pv[dk] = 0.f;
#pragma unroll
        for (int k = 0; k < 8; ++k) {
            const float* vr = Vb + (size_t)(lane + (k << 6)) * DD + h * DKK;
            const float4 va = *(const float4*)vr;
            const float4 vb2 = *(const float4*)(vr + 4);
            const float pk = p[k];
            pv[0] = fmaf(pk, va.x, pv[0]);
            pv[1] = fmaf(pk, va.y, pv[1]);
            pv[2] = fmaf(pk, va.z, pv[2]);
            pv[3] = fmaf(pk, va.w, pv[3]);
            pv[4] = fmaf(pk, vb2.x, pv[4]);
            pv[5] = fmaf(pk, vb2.y, pv[5]);
            pv[6] = fmaf(pk, vb2.z, pv[6]);
            pv[7] = fmaf(pk, vb2.w, pv[7]);
        }
#pragma unroll
        for (int dk = 0; dk < 8; ++dk) {
            float x2 = pv[dk];
            x2 += __shfl_xor(x2, 1, 64);
            x2 += __shfl_xor(x2, 2, 64);
            x2 += __shfl_xor(x2, 4, 64);
            x2 += __shfl_xor(x2, 8, 64);
            x2 += __shfl_xor(x2, 16, 64);
            x2 += __shfl_xor(x2, 32, 64);
            pv[dk] = x2;
        }
        if (lane == 0) {
            const float sc = log1pf(gsum[h]) / s;
#pragma unroll
            for (int dk = 0; dk < 8; ++dk) vh_lds[h * DKK + dk] = pv[dk] * sc;
        }
    }
    __syncthreads();

    // ---- n_out[b,i,:] = vh @ On ----
    if (t < DD) {
        const int j = t;
        float acc = 0.f;
#pragma unroll
        for (int d = 0; d < DD; ++d) acc = fmaf(vh_lds[d], On[d * DD + j], acc);
        n_out[(size_t)row * DD + j] = acc;
    }
}

extern "C" void kernel_launch(void* const* d_in, const int* in_sizes, int n_in,
                              void* d_out, int out_size, void* d_ws, size_t ws_size,
                              hipStream_t stream) {
    const float* n  = (const float*)d_in[0];
    const float* e  = (const float*)d_in[1];
    const float* Wq = (const float*)d_in[2];
    const float* Wk = (const float*)d_in[3];
    const float* Wv = (const float*)d_in[4];
    const float* On = (const float*)d_in[5];
    const float* We = (const float*)d_in[6];
    const float* Wg = (const float*)d_in[7];
    const float* Oe = (const float*)d_in[8];

    float* out = (float*)d_out;
    float* n_out = out;                                  // B*N*D floats
    float* e_out = out + (size_t)BB * NN * DD;           // B*N*N*D floats

    float* Q = (float*)d_ws;
    float* K = Q + (size_t)BB * NN * DD;
    float* V = K + (size_t)BB * NN * DD;

    qkv_kernel<<<BB * NN, 64, 0, stream>>>(n, Wq, Wk, Wv, Q, K, V);
    attn_kernel<<<BB * NN, 256, 0, stream>>>(e, Q, K, V, We, Wg, Oe, On, n_out, e_out);
}

// Round 4
// 360.397 us; speedup vs baseline: 2.5643x; 2.5643x over previous
//
#include <hip/hip_runtime.h>
#include <hip/hip_bf16.h>
#include <math.h>

#define BB 4
#define NN 512
#define DD 64
#define HH 8
#define DKK 8

// ---------------- Kernel 1: QKV projection ----------------
__global__ __launch_bounds__(64) void qkv_kernel(
    const float* __restrict__ n,
    const float* __restrict__ Wq,
    const float* __restrict__ Wk,
    const float* __restrict__ Wv,
    float* __restrict__ Q,
    float* __restrict__ K,
    float* __restrict__ V)
{
    const int row = blockIdx.x;        // b*N + i
    const int j = threadIdx.x;         // 0..63
    __shared__ __align__(16) float nr[DD];
    nr[j] = n[(size_t)row * DD + j];
    __syncthreads();
    float q = 0.f, k = 0.f, v = 0.f;
#pragma unroll
    for (int d = 0; d < DD; ++d) {
        const float nv = nr[d];
        q = fmaf(nv, Wq[d * DD + j], q);
        k = fmaf(nv, Wk[d * DD + j], k);
        v = fmaf(nv, Wv[d * DD + j], v);
    }
    Q[(size_t)row * DD + j] = q;
    K[(size_t)row * DD + j] = k;
    V[(size_t)row * DD + j] = v;
}

// ---------------- Kernel 2: fused edge + attention ----------------
// One block of 256 threads per (b, i). Thread t owns rows m0=t and m1=t+256,
// processed TOGETHER so each LDS weight broadcast serves two rows.
// No VGPR cap (R2's launch_bounds(256,4) forced 64 VGPR -> massive spill).
__global__ __launch_bounds__(256) void attn_kernel(
    const float* __restrict__ e,
    const float* __restrict__ Q,
    const float* __restrict__ K,
    const float* __restrict__ V,
    const float* __restrict__ We,   // [64][8]
    const float* __restrict__ Wg,   // [64][8]
    const float* __restrict__ Oe,   // [8][64]
    const float* __restrict__ On,   // [64][64]
    float* __restrict__ n_out,      // [B][N][64]
    float* __restrict__ e_out)      // [B][N][N][64]
{
    const int row = blockIdx.x;        // b*N + i
    const int b = row >> 9;            // row / 512
    const int t = threadIdx.x;
    const int lane = t & 63;
    const int wv = t >> 6;             // wave id 0..3

    __shared__ __align__(16) float we_l[DD * HH];   // 2 KB
    __shared__ __align__(16) float wg_l[DD * HH];   // 2 KB
    __shared__ __align__(16) float oe_l[HH * DD];   // 2 KB
    __shared__ __align__(16) float q_lds[DD];
    __shared__ float eb_lds[HH][NN];   // 16 KB
    __shared__ float gpart[4][HH];
    __shared__ float gsum[HH];
    __shared__ float vh_lds[DD];

    // stage weights (6 KB) + q once per block
#pragma unroll
    for (int idx = t; idx < DD * HH; idx += 256) {
        we_l[idx] = We[idx];
        wg_l[idx] = Wg[idx];
        oe_l[idx] = Oe[idx];
    }
    if (t < DD) q_lds[t] = Q[(size_t)row * DD + t];
    __syncthreads();

    const float scale = 0.35355339059327373f;  // 1/sqrt(8)
    const float* __restrict__ Kb = K + (size_t)b * NN * DD;

    // ---- Phase 1: A = clip(Q.K * scale) into eb_lds ----
    for (int mm = 0; mm < 2; ++mm) {
        const int m = t + mm * 256;
        const float4* __restrict__ kr = (const float4*)(Kb + (size_t)m * DD);
        float aa[HH];
#pragma unroll
        for (int h = 0; h < HH; ++h) {
            const float4 k0 = kr[2 * h];
            const float4 k1 = kr[2 * h + 1];
            const float4 q0 = *(const float4*)&q_lds[h * 8];
            const float4 q1 = *(const float4*)&q_lds[h * 8 + 4];
            float a = q0.x * k0.x;
            a = fmaf(q0.y, k0.y, a);
            a = fmaf(q0.z, k0.z, a);
            a = fmaf(q0.w, k0.w, a);
            a = fmaf(q1.x, k1.x, a);
            a = fmaf(q1.y, k1.y, a);
            a = fmaf(q1.z, k1.z, a);
            a = fmaf(q1.w, k1.w, a);
            aa[h] = a;
        }
#pragma unroll
        for (int h = 0; h < HH; ++h) {
            float a = aa[h] * scale;
            eb_lds[h][m] = fminf(fmaxf(a, -5.f), 5.f);
        }
    }
    // no barrier: each thread reads back only its own eb_lds entries

    float gs[HH];
#pragma unroll
    for (int h = 0; h < HH; ++h) gs[h] = 0.f;

    const float* __restrict__ e_row_base = e + (size_t)row * NN * DD;
    float* __restrict__ eo_base = e_out + (size_t)row * NN * DD;

    // ---- Phase 2: stream e for BOTH rows at once ----
    const int m0 = t;
    const int m1 = t + 256;
    const float4* __restrict__ er0 = (const float4*)(e_row_base + (size_t)m0 * DD);
    const float4* __restrict__ er1 = (const float4*)(e_row_base + (size_t)m1 * DD);

    float ea0[HH], ga0[HH], ea1[HH], ga1[HH];
#pragma unroll
    for (int h = 0; h < HH; ++h) { ea0[h] = 0.f; ga0[h] = 0.f; ea1[h] = 0.f; ga1[h] = 0.f; }

#pragma unroll 4
    for (int c = 0; c < DD / 4; ++c) {     // 16 float4 chunks of e per row
        const float4 ev0 = er0[c];
        const float4 ev1 = er1[c];
#pragma unroll
        for (int j = 0; j < 4; ++j) {
            const int d = c * 4 + j;
            const float e0 = (j == 0) ? ev0.x : (j == 1) ? ev0.y : (j == 2) ? ev0.z : ev0.w;
            const float e1 = (j == 0) ? ev1.x : (j == 1) ? ev1.y : (j == 2) ? ev1.z : ev1.w;
            const float4 wea = *(const float4*)&we_l[d * HH];
            const float4 web = *(const float4*)&we_l[d * HH + 4];
            const float4 wga = *(const float4*)&wg_l[d * HH];
            const float4 wgb = *(const float4*)&wg_l[d * HH + 4];
            ea0[0] = fmaf(e0, wea.x, ea0[0]);  ea1[0] = fmaf(e1, wea.x, ea1[0]);
            ea0[1] = fmaf(e0, wea.y, ea0[1]);  ea1[1] = fmaf(e1, wea.y, ea1[1]);
            ea0[2] = fmaf(e0, wea.z, ea0[2]);  ea1[2] = fmaf(e1, wea.z, ea1[2]);
            ea0[3] = fmaf(e0, wea.w, ea0[3]);  ea1[3] = fmaf(e1, wea.w, ea1[3]);
            ea0[4] = fmaf(e0, web.x, ea0[4]);  ea1[4] = fmaf(e1, web.x, ea1[4]);
            ea0[5] = fmaf(e0, web.y, ea0[5]);  ea1[5] = fmaf(e1, web.y, ea1[5]);
            ea0[6] = fmaf(e0, web.z, ea0[6]);  ea1[6] = fmaf(e1, web.z, ea1[6]);
            ea0[7] = fmaf(e0, web.w, ea0[7]);  ea1[7] = fmaf(e1, web.w, ea1[7]);
            ga0[0] = fmaf(e0, wga.x, ga0[0]);  ga1[0] = fmaf(e1, wga.x, ga1[0]);
            ga0[1] = fmaf(e0, wga.y, ga0[1]);  ga1[1] = fmaf(e1, wga.y, ga1[1]);
            ga0[2] = fmaf(e0, wga.z, ga0[2]);  ga1[2] = fmaf(e1, wga.z, ga1[2]);
            ga0[3] = fmaf(e0, wga.w, ga0[3]);  ga1[3] = fmaf(e1, wga.w, ga1[3]);
            ga0[4] = fmaf(e0, wgb.x, ga0[4]);  ga1[4] = fmaf(e1, wgb.x, ga1[4]);
            ga0[5] = fmaf(e0, wgb.y, ga0[5]);  ga1[5] = fmaf(e1, wgb.y, ga1[5]);
            ga0[6] = fmaf(e0, wgb.z, ga0[6]);  ga1[6] = fmaf(e1, wgb.z, ga1[6]);
            ga0[7] = fmaf(e0, wgb.w, ga0[7]);  ga1[7] = fmaf(e1, wgb.w, ga1[7]);
        }
    }

    float eb0[HH], eb1[HH];
#pragma unroll
    for (int h = 0; h < HH; ++h) {
        const float v0 = eb_lds[h][m0] + ea0[h];
        const float v1 = eb_lds[h][m1] + ea1[h];
        eb0[h] = v0;
        eb1[h] = v1;
        eb_lds[h][m0] = v0;
        eb_lds[h][m1] = v1;
        gs[h] += 1.f / (1.f + __expf(-ga0[h])) + 1.f / (1.f + __expf(-ga1[h]));
    }

    // e_out rows: each Oe broadcast serves both rows
    float4* __restrict__ eo0 = (float4*)(eo_base + (size_t)m0 * DD);
    float4* __restrict__ eo1 = (float4*)(eo_base + (size_t)m1 * DD);
#pragma unroll 4
    for (int c = 0; c < DD / 4; ++c) {
        float4 a0, a1;
        a0.x = 0.f; a0.y = 0.f; a0.z = 0.f; a0.w = 0.f;
        a1.x = 0.f; a1.y = 0.f; a1.z = 0.f; a1.w = 0.f;
#pragma unroll
        for (int h = 0; h < HH; ++h) {
            const float4 ov = *(const float4*)&oe_l[h * DD + c * 4];
            const float b0 = eb0[h];
            const float b1 = eb1[h];
            a0.x = fmaf(b0, ov.x, a0.x);  a1.x = fmaf(b1, ov.x, a1.x);
            a0.y = fmaf(b0, ov.y, a0.y);  a1.y = fmaf(b1, ov.y, a1.y);
            a0.z = fmaf(b0, ov.z, a0.z);  a1.z = fmaf(b1, ov.z, a1.z);
            a0.w = fmaf(b0, ov.w, a0.w);  a1.w = fmaf(b1, ov.w, a1.w);
        }
        eo0[c] = a0;
        eo1[c] = a1;
    }

    // ---- deterministic G-sum reduction ----
#pragma unroll
    for (int h = 0; h < HH; ++h) {
        float x = gs[h];
        x += __shfl_xor(x, 1, 64);
        x += __shfl_xor(x, 2, 64);
        x += __shfl_xor(x, 4, 64);
        x += __shfl_xor(x, 8, 64);
        x += __shfl_xor(x, 16, 64);
        x += __shfl_xor(x, 32, 64);
        if (lane == 0) gpart[wv][h] = x;
    }
    __syncthreads();
    if (t < HH) gsum[t] = gpart[0][t] + gpart[1][t] + gpart[2][t] + gpart[3][t];
    __syncthreads();

    // ---- softmax + PV: wave wv handles h = wv and wv+4 ----
    const float* __restrict__ Vb = V + (size_t)b * NN * DD;
#pragma unroll
    for (int hh = 0; hh < 2; ++hh) {
        const int h = wv + hh * 4;
        float x[8];
#pragma unroll
        for (int k = 0; k < 8; ++k) x[k] = eb_lds[h][lane + (k << 6)];
        float mx = x[0];
#pragma unroll
        for (int k = 1; k < 8; ++k) mx = fmaxf(mx, x[k]);
        mx = fmaxf(mx, __shfl_xor(mx, 1, 64));
        mx = fmaxf(mx, __shfl_xor(mx, 2, 64));
        mx = fmaxf(mx, __shfl_xor(mx, 4, 64));
        mx = fmaxf(mx, __shfl_xor(mx, 8, 64));
        mx = fmaxf(mx, __shfl_xor(mx, 16, 64));
        mx = fmaxf(mx, __shfl_xor(mx, 32, 64));
        float p[8];
        float s = 0.f;
#pragma unroll
        for (int k = 0; k < 8; ++k) { p[k] = __expf(x[k] - mx); s += p[k]; }
        s += __shfl_xor(s, 1, 64);
        s += __shfl_xor(s, 2, 64);
        s += __shfl_xor(s, 4, 64);
        s += __shfl_xor(s, 8, 64);
        s += __shfl_xor(s, 16, 64);
        s += __shfl_xor(s, 32, 64);

        float pv[8];
#pragma unroll
        for (int dk = 0; dk < 8; ++dk) pv[dk] = 0.f;
#pragma unroll
        for (int k = 0; k < 8; ++k) {
            const float* vr = Vb + (size_t)(lane + (k << 6)) * DD + h * DKK;
            const float4 va = *(const float4*)vr;
            const float4 vb2 = *(const float4*)(vr + 4);
            const float pk = p[k];
            pv[0] = fmaf(pk, va.x, pv[0]);
            pv[1] = fmaf(pk, va.y, pv[1]);
            pv[2] = fmaf(pk, va.z, pv[2]);
            pv[3] = fmaf(pk, va.w, pv[3]);
            pv[4] = fmaf(pk, vb2.x, pv[4]);
            pv[5] = fmaf(pk, vb2.y, pv[5]);
            pv[6] = fmaf(pk, vb2.z, pv[6]);
            pv[7] = fmaf(pk, vb2.w, pv[7]);
        }
#pragma unroll
        for (int dk = 0; dk < 8; ++dk) {
            float x2 = pv[dk];
            x2 += __shfl_xor(x2, 1, 64);
            x2 += __shfl_xor(x2, 2, 64);
            x2 += __shfl_xor(x2, 4, 64);
            x2 += __shfl_xor(x2, 8, 64);
            x2 += __shfl_xor(x2, 16, 64);
            x2 += __shfl_xor(x2, 32, 64);
            pv[dk] = x2;
        }
        if (lane == 0) {
            const float sc = log1pf(gsum[h]) / s;
#pragma unroll
            for (int dk = 0; dk < 8; ++dk) vh_lds[h * DKK + dk] = pv[dk] * sc;
        }
    }
    __syncthreads();

    // ---- n_out[b,i,:] = vh @ On ----
    if (t < DD) {
        const int j = t;
        float acc = 0.f;
#pragma unroll
        for (int d = 0; d < DD; ++d) acc = fmaf(vh_lds[d], On[d * DD + j], acc);
        n_out[(size_t)row * DD + j] = acc;
    }
}

extern "C" void kernel_launch(void* const* d_in, const int* in_sizes, int n_in,
                              void* d_out, int out_size, void* d_ws, size_t ws_size,
                              hipStream_t stream) {
    const float* n  = (const float*)d_in[0];
    const float* e  = (const float*)d_in[1];
    const float* Wq = (const float*)d_in[2];
    const float* Wk = (const float*)d_in[3];
    const float* Wv = (const float*)d_in[4];
    const float* On = (const float*)d_in[5];
    const float* We = (const float*)d_in[6];
    const float* Wg = (const float*)d_in[7];
    const float* Oe = (const float*)d_in[8];

    float* out = (float*)d_out;
    float* n_out = out;                                  // B*N*D floats
    float* e_out = out + (size_t)BB * NN * DD;           // B*N*N*D floats

    float* Q = (float*)d_ws;
    float* K = Q + (size_t)BB * NN * DD;
    float* V = K + (size_t)BB * NN * DD;

    qkv_kernel<<<BB * NN, 64, 0, stream>>>(n, Wq, Wk, Wv, Q, K, V);
    attn_kernel<<<BB * NN, 256, 0, stream>>>(e, Q, K, V, We, Wg, Oe, On, n_out, e_out);
}

// Round 5
// 189.804 us; speedup vs baseline: 4.8691x; 1.8988x over previous
//
#include <hip/hip_runtime.h>
#include <hip/hip_bf16.h>
#include <math.h>

#define BB 4
#define NN 512
#define DD 64
#define HH 8
#define DKK 8

typedef float f32x4 __attribute__((ext_vector_type(4)));
typedef short s16x8 __attribute__((ext_vector_type(8)));

// split fp32 -> bf16 hi + bf16 lo (truncation; residual captured exactly enough:
// total representation error ~2^-16 relative)
__device__ __forceinline__ void split8(const float* fv, s16x8& hi, s16x8& lo) {
#pragma unroll
    for (int j = 0; j < 8; ++j) {
        const unsigned u = __float_as_uint(fv[j]);
        hi[j] = (short)(u >> 16);
        const float r = fv[j] - __uint_as_float(u & 0xFFFF0000u);
        lo[j] = (short)(__float_as_uint(r) >> 16);
    }
}

// ---------------- Kernel 1: QKV projection ----------------
__global__ __launch_bounds__(64) void qkv_kernel(
    const float* __restrict__ n,
    const float* __restrict__ Wq,
    const float* __restrict__ Wk,
    const float* __restrict__ Wv,
    float* __restrict__ Q,
    float* __restrict__ K,
    float* __restrict__ V)
{
    const int row = blockIdx.x;        // b*N + i
    const int j = threadIdx.x;         // 0..63
    __shared__ __align__(16) float nr[DD];
    nr[j] = n[(size_t)row * DD + j];
    __syncthreads();
    float q = 0.f, k = 0.f, v = 0.f;
#pragma unroll
    for (int d = 0; d < DD; ++d) {
        const float nv = nr[d];
        q = fmaf(nv, Wq[d * DD + j], q);
        k = fmaf(nv, Wk[d * DD + j], k);
        v = fmaf(nv, Wv[d * DD + j], v);
    }
    Q[(size_t)row * DD + j] = q;
    K[(size_t)row * DD + j] = k;
    V[(size_t)row * DD + j] = v;
}

// ---------------- Kernel 2: MFMA edge + attention ----------------
// Block = one (b,i), 256 threads = 4 waves. Wave w owns m in [128w, 128w+128)
// as 8 tiles of 16 rows. GEMM1: [16m x 64d] @ [64d x 16(E|G)] via
// mfma_f32_16x16x32_bf16 with hi/lo split (3 products). GEMM2:
// [16m x 8h(pad32)] @ [8h x 64d] for e_out.
__global__ __launch_bounds__(256) void attn_kernel(
    const float* __restrict__ e,
    const float* __restrict__ Q,
    const float* __restrict__ K,
    const float* __restrict__ V,
    const float* __restrict__ We,   // [64][8]
    const float* __restrict__ Wg,   // [64][8]
    const float* __restrict__ Oe,   // [8][64]
    const float* __restrict__ On,   // [64][64]
    float* __restrict__ n_out,      // [B][N][64]
    float* __restrict__ e_out)      // [B][N][N][64]
{
    const int row = blockIdx.x;        // b*N + i
    const int b = row >> 9;
    const int t = threadIdx.x;
    const int lane = t & 63;
    const int wv = t >> 6;             // wave 0..3
    const int cc = lane & 15;          // M-row (A) / N-col (B,C) within tile
    const int kg = lane >> 4;          // k-group 0..3

    __shared__ __align__(16) float q_lds[DD];
    __shared__ __align__(16) float eb_lds[HH][NN];          // 16 KB: A_clip then Eb
    __shared__ __align__(16) unsigned short ehi_w[4][16][8]; // per-wave Eb hi
    __shared__ __align__(16) unsigned short elo_w[4][16][8]; // per-wave Eb lo
    __shared__ float gpart[4][HH];
    __shared__ float gsum[HH];
    __shared__ float vh_lds[DD];

    if (t < DD) q_lds[t] = Q[(size_t)row * DD + t];
    __syncthreads();

    // ---- Phase A: A_clip = clip(Q.K * scale) into eb_lds (verified R3 code) ----
    const float scale = 0.35355339059327373f;
    const float* __restrict__ Kb = K + (size_t)b * NN * DD;
    for (int mm = 0; mm < 2; ++mm) {
        const int m = t + mm * 256;
        const float4* __restrict__ kr = (const float4*)(Kb + (size_t)m * DD);
#pragma unroll
        for (int h = 0; h < HH; ++h) {
            const float4 k0 = kr[2 * h];
            const float4 k1 = kr[2 * h + 1];
            const float4 q0 = *(const float4*)&q_lds[h * 8];
            const float4 q1 = *(const float4*)&q_lds[h * 8 + 4];
            float a = q0.x * k0.x;
            a = fmaf(q0.y, k0.y, a);
            a = fmaf(q0.z, k0.z, a);
            a = fmaf(q0.w, k0.w, a);
            a = fmaf(q1.x, k1.x, a);
            a = fmaf(q1.y, k1.y, a);
            a = fmaf(q1.z, k1.z, a);
            a = fmaf(q1.w, k1.w, a);
            a *= scale;
            eb_lds[h][m] = fminf(fmaxf(a, -5.f), 5.f);
        }
    }
    __syncthreads();

    // ---- Weight fragments (once per block, register-resident) ----
    // B1: Wc[k][c] with Wc = [We | Wg]; k = ks*32 + kg*8 + j, c = cc
    s16x8 b1h[2], b1l[2];
#pragma unroll
    for (int ks = 0; ks < 2; ++ks) {
        float fv[8];
#pragma unroll
        for (int j = 0; j < 8; ++j) {
            const int k = ks * 32 + kg * 8 + j;
            fv[j] = (cc < 8) ? We[k * HH + cc] : Wg[k * HH + (cc - 8)];
        }
        split8(fv, b1h[ks], b1l[ks]);
    }
    // B2: Oe[k][d], d = nt*16 + cc; k = kg*8 + j, valid only kg==0 (K padded 8->32)
    s16x8 b2h[4], b2l[4];
#pragma unroll
    for (int nt = 0; nt < 4; ++nt) {
        float fv[8];
#pragma unroll
        for (int j = 0; j < 8; ++j)
            fv[j] = (kg == 0) ? Oe[j * DD + nt * 16 + cc] : 0.f;
        split8(fv, b2h[nt], b2l[nt]);
    }

    // ---- Main loop over this wave's 8 m-tiles ----
    float gs_loc = 0.f;   // lanes with cc>=8 accumulate sigmoid(G) for h=cc-8
    const float* __restrict__ e_row = e + (size_t)row * NN * DD;
    float* __restrict__ eo = e_out + (size_t)row * NN * DD;

    for (int T = wv * 8; T < wv * 8 + 8; ++T) {
        const int m0 = T * 16;
        // A1 frags: e[m0+cc][ks*32 + kg*8 + j]
        s16x8 a1h[2], a1l[2];
#pragma unroll
        for (int ks = 0; ks < 2; ++ks) {
            const float* src = e_row + (size_t)(m0 + cc) * DD + ks * 32 + kg * 8;
            const float4 fa = *(const float4*)src;
            const float4 fb = *(const float4*)(src + 4);
            float fv[8];
            fv[0] = fa.x; fv[1] = fa.y; fv[2] = fa.z; fv[3] = fa.w;
            fv[4] = fb.x; fv[5] = fb.y; fv[6] = fb.z; fv[7] = fb.w;
            split8(fv, a1h[ks], a1l[ks]);
        }
        // GEMM1: C[m][c] = e @ [We|Wg]
        f32x4 acc = {0.f, 0.f, 0.f, 0.f};
#pragma unroll
        for (int ks = 0; ks < 2; ++ks) {
            acc = __builtin_amdgcn_mfma_f32_16x16x32_bf16(a1h[ks], b1h[ks], acc, 0, 0, 0);
            acc = __builtin_amdgcn_mfma_f32_16x16x32_bf16(a1l[ks], b1h[ks], acc, 0, 0, 0);
            acc = __builtin_amdgcn_mfma_f32_16x16x32_bf16(a1h[ks], b1l[ks], acc, 0, 0, 0);
        }
        // post: C row = kg*4 + r, col = cc
        if (cc < 8) {
#pragma unroll
            for (int r = 0; r < 4; ++r) {
                const int mr = kg * 4 + r;
                const int m = m0 + mr;
                const float ebv = eb_lds[cc][m] + acc[r];   // Eb = A_clip + E
                eb_lds[cc][m] = ebv;                         // for softmax
                const unsigned u = __float_as_uint(ebv);
                ehi_w[wv][mr][cc] = (unsigned short)(u >> 16);
                const float rr = ebv - __uint_as_float(u & 0xFFFF0000u);
                elo_w[wv][mr][cc] = (unsigned short)(__float_as_uint(rr) >> 16);
            }
        } else {
#pragma unroll
            for (int r = 0; r < 4; ++r)
                gs_loc += 1.f / (1.f + __expf(-acc[r]));
        }
        // A2 frags: Eb[m0+l][h=j] for lanes l<16 (k-groups >=1 are zero padding)
        s16x8 a2h = {0, 0, 0, 0, 0, 0, 0, 0};
        s16x8 a2l = {0, 0, 0, 0, 0, 0, 0, 0};
        if (lane < 16) {
            a2h = *(const s16x8*)&ehi_w[wv][lane][0];
            a2l = *(const s16x8*)&elo_w[wv][lane][0];
        }
        // GEMM2: e_out[m][d] = Eb @ Oe
#pragma unroll
        for (int nt = 0; nt < 4; ++nt) {
            f32x4 c2 = {0.f, 0.f, 0.f, 0.f};
            c2 = __builtin_amdgcn_mfma_f32_16x16x32_bf16(a2h, b2h[nt], c2, 0, 0, 0);
            c2 = __builtin_amdgcn_mfma_f32_16x16x32_bf16(a2l, b2h[nt], c2, 0, 0, 0);
            c2 = __builtin_amdgcn_mfma_f32_16x16x32_bf16(a2h, b2l[nt], c2, 0, 0, 0);
#pragma unroll
            for (int r = 0; r < 4; ++r) {
                const int m = m0 + kg * 4 + r;
                eo[(size_t)m * DD + nt * 16 + cc] = c2[r];
            }
        }
    }

    // ---- G reduction: lanes {8+h, 24+h, 40+h, 56+h} hold partials ----
    {
        float x = gs_loc;
        x += __shfl_xor(x, 16, 64);
        x += __shfl_xor(x, 32, 64);
        if (lane >= 8 && lane < 16) gpart[wv][lane - 8] = x;
    }
    __syncthreads();
    if (t < HH) gsum[t] = gpart[0][t] + gpart[1][t] + gpart[2][t] + gpart[3][t];
    __syncthreads();

    // ---- softmax + PV: wave wv handles h = wv and wv+4 (verified R3 code) ----
    const float* __restrict__ Vb = V + (size_t)b * NN * DD;
#pragma unroll
    for (int hh = 0; hh < 2; ++hh) {
        const int h = wv + hh * 4;
        float x[8];
#pragma unroll
        for (int k = 0; k < 8; ++k) x[k] = eb_lds[h][lane + (k << 6)];
        float mx = x[0];
#pragma unroll
        for (int k = 1; k < 8; ++k) mx = fmaxf(mx, x[k]);
        mx = fmaxf(mx, __shfl_xor(mx, 1, 64));
        mx = fmaxf(mx, __shfl_xor(mx, 2, 64));
        mx = fmaxf(mx, __shfl_xor(mx, 4, 64));
        mx = fmaxf(mx, __shfl_xor(mx, 8, 64));
        mx = fmaxf(mx, __shfl_xor(mx, 16, 64));
        mx = fmaxf(mx, __shfl_xor(mx, 32, 64));
        float p[8];
        float s = 0.f;
#pragma unroll
        for (int k = 0; k < 8; ++k) { p[k] = __expf(x[k] - mx); s += p[k]; }
        s += __shfl_xor(s, 1, 64);
        s += __shfl_xor(s, 2, 64);
        s += __shfl_xor(s, 4, 64);
        s += __shfl_xor(s, 8, 64);
        s += __shfl_xor(s, 16, 64);
        s += __shfl_xor(s, 32, 64);

        float pv[8];
#pragma unroll
        for (int dk = 0; dk < 8; ++dk) pv[dk] = 0.f;
#pragma unroll
        for (int k = 0; k < 8; ++k) {
            const float* vr = Vb + (size_t)(lane + (k << 6)) * DD + h * DKK;
            const float4 va = *(const float4*)vr;
            const float4 vb2 = *(const float4*)(vr + 4);
            const float pk = p[k];
            pv[0] = fmaf(pk, va.x, pv[0]);
            pv[1] = fmaf(pk, va.y, pv[1]);
            pv[2] = fmaf(pk, va.z, pv[2]);
            pv[3] = fmaf(pk, va.w, pv[3]);
            pv[4] = fmaf(pk, vb2.x, pv[4]);
            pv[5] = fmaf(pk, vb2.y, pv[5]);
            pv[6] = fmaf(pk, vb2.z, pv[6]);
            pv[7] = fmaf(pk, vb2.w, pv[7]);
        }
#pragma unroll
        for (int dk = 0; dk < 8; ++dk) {
            float x2 = pv[dk];
            x2 += __shfl_xor(x2, 1, 64);
            x2 += __shfl_xor(x2, 2, 64);
            x2 += __shfl_xor(x2, 4, 64);
            x2 += __shfl_xor(x2, 8, 64);
            x2 += __shfl_xor(x2, 16, 64);
            x2 += __shfl_xor(x2, 32, 64);
            pv[dk] = x2;
        }
        if (lane == 0) {
            const float sc = log1pf(gsum[h]) / s;
#pragma unroll
            for (int dk = 0; dk < 8; ++dk) vh_lds[h * DKK + dk] = pv[dk] * sc;
        }
    }
    __syncthreads();

    // ---- n_out[b,i,:] = vh @ On ----
    if (t < DD) {
        const int j = t;
        float acc = 0.f;
#pragma unroll
        for (int d = 0; d < DD; ++d) acc = fmaf(vh_lds[d], On[d * DD + j], acc);
        n_out[(size_t)row * DD + j] = acc;
    }
}

extern "C" void kernel_launch(void* const* d_in, const int* in_sizes, int n_in,
                              void* d_out, int out_size, void* d_ws, size_t ws_size,
                              hipStream_t stream) {
    const float* n  = (const float*)d_in[0];
    const float* e  = (const float*)d_in[1];
    const float* Wq = (const float*)d_in[2];
    const float* Wk = (const float*)d_in[3];
    const float* Wv = (const float*)d_in[4];
    const float* On = (const float*)d_in[5];
    const float* We = (const float*)d_in[6];
    const float* Wg = (const float*)d_in[7];
    const float* Oe = (const float*)d_in[8];

    float* out = (float*)d_out;
    float* n_out = out;                                  // B*N*D floats
    float* e_out = out + (size_t)BB * NN * DD;           // B*N*N*D floats

    float* Q = (float*)d_ws;
    float* K = Q + (size_t)BB * NN * DD;
    float* V = K + (size_t)BB * NN * DD;

    qkv_kernel<<<BB * NN, 64, 0, stream>>>(n, Wq, Wk, Wv, Q, K, V);
    attn_kernel<<<BB * NN, 256, 0, stream>>>(e, Q, K, V, We, Wg, Oe, On, n_out, e_out);
}